// Round 16
// baseline (77.777 us; speedup 1.0000x reference)
//
#include <hip/hip_runtime.h>
#include <hip/hip_bf16.h>

// Locally-connected 2D: out[b,o,y,x] = sum_{c,kh,kw} x[b,c,y+kh,x+kw] * W[y,x,o,c*25+kh*5+kw] + b[y,x,o]
// x: [128,3,64,64] f32, W: [60,60,32,75] f32, bias: [60,60,32] f32, out: [128,32,60,60] f32.
//
// 1) wpack (verified r13): W (+bias) -> Wp[pos][o][128] bf16 in EXACT MFMA B-fragment
//    order: k' = cm*8 + w (cm=c*5+kh), window [xi,xi+5) holds W (xi=pos%4 baked via
//    funnel shift), slot 120 = bias (consumed by one-hot A=1.0).
// 2) main v4 (r16): INLINE-ASM loads. r14/r15 proved the compiler sinks/remats
//    C++ loads regardless of sched_barrier (VGPR 28/52). asm volatile
//    global_load_dwordx4 pins 24 live destinations/lane -> 24 loads in flight.
//    Counted waits: vmcnt(16) -> pack A (overlaps B returns) -> vmcnt(0) -> MFMA.
//    Each waitcnt followed by sched_barrier(0) (rule #18). cm==15 handled by
//    address clamp + ?: fragment patch (no divergence, one scheduling region).

#define RY 60
#define RX 60
#define OC 32
#define BATCH 128
#define CIN 3
#define HW 64
#define NPOS 3600
#define KPACK 128

typedef __attribute__((ext_vector_type(8))) short short8;
typedef __attribute__((ext_vector_type(4))) float f32x4;
typedef unsigned long long ull;

__device__ __forceinline__ ushort bf16u(float f) {
    __hip_bfloat16 h = __float2bfloat16(f);
    return *reinterpret_cast<ushort*>(&h);
}
__device__ __forceinline__ unsigned pk2(float a, float b) {
    return (unsigned)bf16u(a) | ((unsigned)bf16u(b) << 16);
}
__device__ __forceinline__ int swz900(int id) {   // bijective XCD chunking for 900
    const int xcd = id & 7, ii = id >> 3;
    return (xcd < 4 ? xcd * 113 : 452 + (xcd - 4) * 112) + ii;
}

// ---------------- prepass: W + bias -> packed bf16 fragments ----------------
__global__ __launch_bounds__(256, 4) void lc2d_wpack(
    const float* __restrict__ w, const float* __restrict__ bias,
    ushort* __restrict__ wp)
{
    __shared__ __align__(16) float wlds[9600 + 128];   // 4 positions x 2400 f32

    const int G   = swz900(blockIdx.x);
    const int tid = threadIdx.x;
    const int lane = tid & 63, wid = tid >> 6;

    {   // async DMA: 38.4KB contiguous W for positions 4G..4G+4
        const float* gW = w + (size_t)G * 4 * (OC * 75);
        for (int j = wid; j < 38; j += 4) {
            const int chunk0 = j * 64;
            int ci = chunk0 + lane;
            if (ci > 2399) ci = 2399;
            __builtin_amdgcn_global_load_lds(
                (const __attribute__((address_space(1))) unsigned*)(gW + ci * 4),
                (__attribute__((address_space(3))) unsigned*)&wlds[chunk0 * 4],
                16, 0, 0);
        }
    }

    const int xi = tid >> 6, o = (tid >> 1) & 31, half = tid & 1;
    const float bv = bias[(size_t)(G * 4 + xi) * OC + o];
    __syncthreads();

    const float* src = &wlds[xi * 2400 + o * 75];
    const int s = xi * 16;
    unsigned wd[32];
    #pragma unroll
    for (int i = 0; i < 32; ++i) wd[i] = 0u;

    #pragma unroll
    for (int cc = 0; cc < 8; ++cc) {
        const int cm = half * 8 + cc;
        if (cm < 15) {
            const float* sp = src + cm * 5;
            const ushort h0 = bf16u(sp[0]), h1 = bf16u(sp[1]), h2 = bf16u(sp[2]),
                         h3 = bf16u(sp[3]), h4 = bf16u(sp[4]);
            const ull lo = (ull)h0 | ((ull)h1 << 16) | ((ull)h2 << 32) | ((ull)h3 << 48);
            const ull hi = (ull)h4;
            const ull rlo = lo << s;
            const ull rhi = (hi << s) | (s ? (lo >> (64 - s)) : 0ull);
            wd[cc * 4 + 0] = (unsigned)rlo;
            wd[cc * 4 + 1] = (unsigned)(rlo >> 32);
            wd[cc * 4 + 2] = (unsigned)rhi;
            wd[cc * 4 + 3] = (unsigned)(rhi >> 32);
        } else {
            wd[cc * 4 + 0] = (unsigned)bf16u(bv);      // k'=120 slot = bias
        }
    }
    ushort* dst = wp + ((size_t)(G * 4 + xi) * OC + o) * KPACK + half * 64;
    #pragma unroll
    for (int q = 0; q < 8; ++q)
        *reinterpret_cast<uint4*>(dst + q * 8) =
            make_uint4(wd[q * 4], wd[q * 4 + 1], wd[q * 4 + 2], wd[q * 4 + 3]);
}

// ---------------- main v4: inline-asm pinned-MLP fused GEMM ----------------
__global__ __launch_bounds__(256, 2) void lc2d_main(
    const float* __restrict__ x, const ushort* __restrict__ wp,
    float* __restrict__ out)
{
    const int id  = blockIdx.x;
    const int lin = (id & 7) * 450 + (id >> 3);   // same-XCD runs; bs fastest
    const int bs  = lin & 3;
    const int G   = lin >> 2;                     // [0,900)
    const int y   = G / 15;
    const int x0  = (G - y * 15) * 4;
    const int pos0 = y * RX + x0;                 // %4 == 0 -> 16B-aligned stores

    const int lane = threadIdx.x & 63, wid = threadIdx.x >> 6;
    const int lrow = lane & 15, lgrp = lane >> 4;
    const int mt = wid >> 1, nt = wid & 1;
    const int bbase = bs * 32 + mt * 16;
    const int o = nt * 16 + lrow;
    const int b = bbase + lrow;

    // ---- addresses (A: clamp cm==15 to cm=0; fragment patched later) ----
    const float* asrc[4];
    #pragma unroll
    for (int ks = 0; ks < 4; ++ks) {
        int cm = ks * 4 + lgrp;
        if (cm >= 15) cm = 0;                     // safe row; value unused
        const int c = cm / 5, kh = cm - c * 5;
        asrc[ks] = x + (size_t)((b * CIN + c) * HW + (y + kh)) * HW + x0;
    }
    const ushort* bsrc[4];
    #pragma unroll
    for (int xi = 0; xi < 4; ++xi)
        bsrc[xi] = wp + ((size_t)(4 * G + xi) * OC + o) * KPACK + lgrp * 8;

    // ---- issue ALL loads via inline asm (destinations pinned live) ----
    float4 av[4][2];
    short8 bfr[4][4];
    #pragma unroll
    for (int ks = 0; ks < 4; ++ks) {
        asm volatile("global_load_dwordx4 %0, %1, off"
                     : "=v"(av[ks][0]) : "v"(asrc[ks]));
        asm volatile("global_load_dwordx4 %0, %1, off offset:16"
                     : "=v"(av[ks][1]) : "v"(asrc[ks]));
    }
    #pragma unroll
    for (int xi = 0; xi < 4; ++xi) {
        asm volatile("global_load_dwordx4 %0, %1, off"
                     : "=v"(bfr[xi][0]) : "v"(bsrc[xi]));
        asm volatile("global_load_dwordx4 %0, %1, off offset:64"
                     : "=v"(bfr[xi][1]) : "v"(bsrc[xi]));
        asm volatile("global_load_dwordx4 %0, %1, off offset:128"
                     : "=v"(bfr[xi][2]) : "v"(bsrc[xi]));
        asm volatile("global_load_dwordx4 %0, %1, off offset:192"
                     : "=v"(bfr[xi][3]) : "v"(bsrc[xi]));
    }

    // ---- A arrived (16 B-loads still outstanding) ----
    asm volatile("s_waitcnt vmcnt(16)");
    __builtin_amdgcn_sched_barrier(0);

    // ---- pack A; (ks==3 && lgrp==3) lane -> one-hot 1.0 @ k'=120 (bias row) ----
    short8 af[4];
    #pragma unroll
    for (int ks = 0; ks < 4; ++ks) {
        const bool pad = (ks * 4 + lgrp) >= 15;
        union { unsigned u[4]; short8 s8; } cv;
        cv.u[0] = pad ? 0x3f80u : pk2(av[ks][0].x, av[ks][0].y);
        cv.u[1] = pad ? 0u      : pk2(av[ks][0].z, av[ks][0].w);
        cv.u[2] = pad ? 0u      : pk2(av[ks][1].x, av[ks][1].y);
        cv.u[3] = pad ? 0u      : pk2(av[ks][1].z, av[ks][1].w);
        af[ks] = cv.s8;
    }

    // ---- B arrived ----
    asm volatile("s_waitcnt vmcnt(0)");
    __builtin_amdgcn_sched_barrier(0);

    // ---- 16 MFMA ----
    f32x4 accx[4];
    #pragma unroll
    for (int xi = 0; xi < 4; ++xi) accx[xi] = (f32x4){0.f, 0.f, 0.f, 0.f};
    #pragma unroll
    for (int xi = 0; xi < 4; ++xi)
        #pragma unroll
        for (int ks = 0; ks < 4; ++ks)
            accx[xi] = __builtin_amdgcn_mfma_f32_16x16x32_bf16(af[ks], bfr[xi][ks], accx[xi], 0, 0, 0);

    // ---- store: per (b,o) one aligned float4 of the 4 consecutive x ----
    #pragma unroll
    for (int r = 0; r < 4; ++r) {
        const int bg = bbase + lgrp * 4 + r;
        f32x4 v = (f32x4){accx[0][r], accx[1][r], accx[2][r], accx[3][r]};
        *reinterpret_cast<f32x4*>(out + (size_t)(bg * OC + o) * NPOS + pos0) = v;
    }
}

// ---------------- fallback (round-10 fused, no workspace) ----------------
__global__ __launch_bounds__(256, 4) void lc2d_fb(
    const float* __restrict__ x, const float* __restrict__ w,
    const float* __restrict__ bias, float* __restrict__ out)
{
    __shared__ __align__(16) float wlds[4 * 2400 + 128];
    const int tid = threadIdx.x;
    const int id  = blockIdx.x;
    const int lin = (id & 7) * 450 + (id >> 3);
    const int bs  = lin & 3;
    const int pg  = lin >> 2;
    const int y   = pg / 15;
    const int x0  = (pg - y * 15) * 4;
    const int pos0 = y * RX + x0;
    const int lane = tid & 63, wid = tid >> 6;
    const int lrow = lane & 15, lgrp = lane >> 4;
    const int mt = wid >> 1, nt = wid & 1;
    const int bbase = bs * 32 + mt * 16;
    const int o = nt * 16 + lrow;

    float4 av[4][2];
    #pragma unroll
    for (int ks = 0; ks < 4; ++ks) {
        const int cm = ks * 4 + lgrp;
        if (cm < 15) {
            const int c = cm / 5, kh = cm - c * 5;
            const int b = bbase + lrow;
            const float* src = x + (size_t)((b * CIN + c) * HW + (y + kh)) * HW + x0;
            av[ks][0] = *(const float4*)(src);
            av[ks][1] = *(const float4*)(src + 4);
        }
    }
    {
        const float* gW = w + (size_t)pos0 * 2400;
        for (int j = wid; j < 38; j += 4) {
            const int chunk0 = j * 64;
            int ci = chunk0 + lane;
            if (ci > 2399) ci = 2399;
            __builtin_amdgcn_global_load_lds(
                (const __attribute__((address_space(1))) unsigned*)(gW + ci * 4),
                (__attribute__((address_space(3))) unsigned*)&wlds[chunk0 * 4],
                16, 0, 0);
        }
    }
    float bv[4];
    #pragma unroll
    for (int xi = 0; xi < 4; ++xi) bv[xi] = bias[(size_t)(pos0 + xi) * OC + o];

    short8 af[4];
    #pragma unroll
    for (int ks = 0; ks < 4; ++ks) {
        const int cm = ks * 4 + lgrp;
        union { unsigned u[4]; short8 s8; } cv;
        if (cm < 15) {
            cv.u[0] = pk2(av[ks][0].x, av[ks][0].y); cv.u[1] = pk2(av[ks][0].z, av[ks][0].w);
            cv.u[2] = pk2(av[ks][1].x, av[ks][1].y); cv.u[3] = pk2(av[ks][1].z, av[ks][1].w);
        } else { cv.u[0] = cv.u[1] = cv.u[2] = cv.u[3] = 0u; }
        af[ks] = cv.s8;
    }
    __syncthreads();

    f32x4 accx[4];
    #pragma unroll
    for (int xi = 0; xi < 4; ++xi) accx[xi] = (f32x4){0.f, 0.f, 0.f, 0.f};
    const int wbase = o * 75;
    #pragma unroll
    for (int ks = 0; ks < 4; ++ks) {
        const int cm = ks * 4 + lgrp;
        const int soff = wbase + cm * 5;
        #pragma unroll
        for (int xi = 0; xi < 4; ++xi) {
            const float* s = &wlds[xi * 2400 + soff];
            const ushort h[5] = {bf16u(s[0]), bf16u(s[1]), bf16u(s[2]), bf16u(s[3]), bf16u(s[4])};
            unsigned wd[4] = {0u, 0u, 0u, 0u};
            #pragma unroll
            for (int kw = 0; kw < 5; ++kw) {
                const int ws = xi + kw;
                wd[ws >> 1] |= (unsigned)h[kw] << ((ws & 1) * 16);
            }
            union { unsigned u[4]; short8 s8; } cv;
            cv.u[0] = wd[0]; cv.u[1] = wd[1]; cv.u[2] = wd[2]; cv.u[3] = wd[3];
            accx[xi] = __builtin_amdgcn_mfma_f32_16x16x32_bf16(af[ks], cv.s8, accx[xi], 0, 0, 0);
        }
    }
    #pragma unroll
    for (int r = 0; r < 4; ++r) {
        const int bg = bbase + lgrp * 4 + r;
        float4 v;
        v.x = accx[0][r] + bv[0]; v.y = accx[1][r] + bv[1];
        v.z = accx[2][r] + bv[2]; v.w = accx[3][r] + bv[3];
        *(float4*)(out + (size_t)(bg * OC + o) * (RY * RX) + pos0) = v;
    }
}

extern "C" void kernel_launch(void* const* d_in, const int* in_sizes, int n_in,
                              void* d_out, int out_size, void* d_ws, size_t ws_size,
                              hipStream_t stream) {
    const float* x    = (const float*)d_in[0];
    const float* w    = (const float*)d_in[1];
    const float* bias = (const float*)d_in[2];
    float* out        = (float*)d_out;

    const size_t wp_bytes = (size_t)NPOS * OC * KPACK * sizeof(ushort);  // 29.5 MB
    if (ws_size >= wp_bytes) {
        ushort* wp = (ushort*)d_ws;
        lc2d_wpack<<<900, 256, 0, stream>>>(w, bias, wp);
        lc2d_main<<<3600, 256, 0, stream>>>(x, wp, out);
    } else {
        lc2d_fb<<<3600, 256, 0, stream>>>(x, w, bias, out);
    }
}

// Round 17
// 58.240 us; speedup vs baseline: 1.3355x; 1.3355x over previous
//
#include <hip/hip_runtime.h>
#include <hip/hip_bf16.h>

// Locally-connected 2D: out[b,o,y,x] = sum_{c,kh,kw} x[b,c,y+kh,x+kw] * W[y,x,o,c*25+kh*5+kw] + b[y,x,o]
// x: [128,3,64,64] f32, W: [60,60,32,75] f32, bias: [60,60,32] f32, out: [128,32,60,60] f32.
//
// Two-phase (r9 champion, k1 rebuilt):
// k1: block = 2 consecutive x positions, M=128 (512 thr, 8 waves of 16 b-rows).
//   k' = cm*8 + w (cm=c*5+kh, w = x-window offset in [0,8); B zero outside [xi,xi+5)).
//   - W (4800 f32 contiguous) -> LDS raw via async global_load_lds (19 x 1KB).
//   - A direct from global per lane (4 float2 per ks, 8B-aligned; slots 6,7 nullified by B).
//   - B fragments packed cooperatively in LDS (960 groups, funnel shift, 2/thread) into
//     fragment-ordered wpk[xi][ks][lgrp][o][8] -> consumption = 16 conflict-free ds_read_b128.
//   - launch_bounds(512,6): 24 waves/CU (vs r9's 16). Two barriers total.
//   - epilogue: bf16 tmp[pos][b*32+o] (+bias), coalesced 32B runs.
// k2 (verified r9): bf16 tmp -> f32 out transpose.

#define RY 60
#define RX 60
#define OC 32
#define BATCH 128
#define CIN 3
#define HW 64
#define NPOS 3600

typedef __attribute__((ext_vector_type(8))) short short8;
typedef __attribute__((ext_vector_type(4))) float f32x4;
typedef unsigned long long ull;

__device__ __forceinline__ ushort bf16u(float f) {
    __hip_bfloat16 h = __float2bfloat16(f);
    return *reinterpret_cast<ushort*>(&h);
}
__device__ __forceinline__ unsigned pk2(float a, float b) {
    return (unsigned)bf16u(a) | ((unsigned)bf16u(b) << 16);
}

// ---------------- k1: per-position GEMM, M=128, XT=2 ----------------
__global__ __launch_bounds__(512, 6) void lc2d_k1(
    const float* __restrict__ x, const float* __restrict__ w,
    const float* __restrict__ bias, ushort* __restrict__ tmp)
{
    __shared__ __align__(16) float wlds[4800 + 128];        // raw W, 19.7 KB
    __shared__ __align__(16) ushort wpk[2][4][4][OC][8];    // packed B frags, 16 KB

    const int tid = threadIdx.x;
    // XCD-chunked bijective mapping: 1800 = 8 x 225
    const int id  = blockIdx.x;
    const int lin = (id & 7) * 225 + (id >> 3);
    const int xp  = lin % 30;
    const int y   = lin / 30;
    const int x0  = xp * 2;
    const int pos0 = y * RX + x0;

    const int lane = tid & 63, wid = tid >> 6;   // 8 waves
    const int lrow = lane & 15, lgrp = lane >> 4;
    const int mbase = wid * 16;                  // 16 b-rows per wave
    const int b = mbase + lrow;

    // ---- issue A loads first (16 float2; window of 8 floats from even x0) ----
    const int xtail = (x0 == 58) ? 4 : 6;        // clamp last load in-bounds (slots 6,7 unused)
    float2 av[4][4];
    #pragma unroll
    for (int ks = 0; ks < 4; ++ks) {
        const int cm = ks * 4 + lgrp;
        if (cm < 15) {
            const int c  = cm / 5;
            const int kh = cm - c * 5;
            const float* src = x + (size_t)((b * CIN + c) * HW + (y + kh)) * HW + x0;
            av[ks][0] = *(const float2*)(src);
            av[ks][1] = *(const float2*)(src + 2);
            av[ks][2] = *(const float2*)(src + 4);
            av[ks][3] = *(const float2*)(src + xtail);
        }
    }

    // ---- async W DMA: 4800 f32 contiguous = 1200 float4, 19 x 1KB chunks ----
    {
        const float* gW = w + (size_t)pos0 * 2400;
        for (int j = wid; j < 19; j += 8) {
            const int chunk0 = j * 64;
            int ci = chunk0 + lane;
            if (ci > 1199) ci = 1199;
            __builtin_amdgcn_global_load_lds(
                (const __attribute__((address_space(1))) unsigned*)(gW + ci * 4),
                (__attribute__((address_space(3))) unsigned*)&wlds[chunk0 * 4],
                16, 0, 0);
        }
    }

    // ---- bias prefetch ----
    float bb[2][2];   // [xi][nt]
    #pragma unroll
    for (int xi = 0; xi < 2; ++xi) {
        bb[xi][0] = bias[(size_t)(pos0 + xi) * OC + lrow];
        bb[xi][1] = bias[(size_t)(pos0 + xi) * OC + 16 + lrow];
    }

    // ---- pack A fragments (overlaps DMA); cm==15 -> zero ----
    short8 af[4];
    #pragma unroll
    for (int ks = 0; ks < 4; ++ks) {
        const bool pad = (ks * 4 + lgrp) >= 15;
        union { unsigned u[4]; short8 s8; } cv;
        cv.u[0] = pad ? 0u : pk2(av[ks][0].x, av[ks][0].y);
        cv.u[1] = pad ? 0u : pk2(av[ks][1].x, av[ks][1].y);
        cv.u[2] = pad ? 0u : pk2(av[ks][2].x, av[ks][2].y);
        cv.u[3] = pad ? 0u : pk2(av[ks][3].x, av[ks][3].y);   // slots 6,7: B zeros nullify
        af[ks] = cv.s8;
    }

    __syncthreads();   // raw W in LDS

    // ---- cooperative B pack: 1024 groups, 2 per thread ----
    #pragma unroll
    for (int p = 0; p < 2; ++p) {
        const int g = tid + p * 512;
        if (g < 960) {
            const int xi = g / 480;
            const int r  = g - xi * 480;
            const int o  = r / 15;
            const int cm = r - o * 15;
            const float* sp = &wlds[xi * 2400 + o * 75 + cm * 5];
            const ushort h0 = bf16u(sp[0]), h1 = bf16u(sp[1]), h2 = bf16u(sp[2]),
                         h3 = bf16u(sp[3]), h4 = bf16u(sp[4]);
            const ull lo = (ull)h0 | ((ull)h1 << 16) | ((ull)h2 << 32) | ((ull)h3 << 48);
            const int s = xi * 16;
            const ull rlo = lo << s;
            const ull rhi = (((ull)h4) << s) | (s ? (lo >> (64 - s)) : 0ull);
            *reinterpret_cast<uint4*>(&wpk[xi][cm >> 2][cm & 3][o][0]) =
                make_uint4((unsigned)rlo, (unsigned)(rlo >> 32),
                           (unsigned)rhi, (unsigned)(rhi >> 32));
        } else {
            const int z = g - 960;
            *reinterpret_cast<uint4*>(&wpk[z >> 5][3][3][z & 31][0]) =
                make_uint4(0u, 0u, 0u, 0u);
        }
    }
    __syncthreads();   // packed B ready

    // ---- MFMA: acc[nt][xi], 16 ds_read_b128 + 16 MFMA ----
    f32x4 acc[2][2];
    #pragma unroll
    for (int nt = 0; nt < 2; ++nt)
        #pragma unroll
        for (int xi = 0; xi < 2; ++xi)
            acc[nt][xi] = (f32x4){0.f, 0.f, 0.f, 0.f};

    #pragma unroll
    for (int nt = 0; nt < 2; ++nt) {
        const int o = nt * 16 + lrow;
        #pragma unroll
        for (int xi = 0; xi < 2; ++xi) {
            #pragma unroll
            for (int ks = 0; ks < 4; ++ks) {
                const short8 bf = *(const short8*)&wpk[xi][ks][lgrp][o][0];
                acc[nt][xi] = __builtin_amdgcn_mfma_f32_16x16x32_bf16(af[ks], bf, acc[nt][xi], 0, 0, 0);
            }
        }
    }

    // ---- epilogue: bf16 tmp[pos][b*32+o] ----
    #pragma unroll
    for (int xi = 0; xi < 2; ++xi) {
        ushort* tb = tmp + (size_t)(pos0 + xi) * (BATCH * OC);
        #pragma unroll
        for (int nt = 0; nt < 2; ++nt) {
            const int o = nt * 16 + lrow;
            #pragma unroll
            for (int r = 0; r < 4; ++r) {
                const int bg = mbase + lgrp * 4 + r;
                tb[bg * OC + o] = bf16u(acc[nt][xi][r] + bb[xi][nt]);
            }
        }
    }
}

// ---------------- k2 (verified r9): bf16 tmp [pos][c] -> f32 out [c][pos] ----------------
__global__ __launch_bounds__(256) void lc2d_k2(
    const ushort* __restrict__ tmp, float* __restrict__ out)
{
    __shared__ float tile[64][61];
    const int y  = blockIdx.y;
    const int cb = blockIdx.x * 64;

    for (int i = threadIdx.x; i < RX * 32; i += 256) {
        const int xx = i >> 5;
        const int cp = i & 31;
        const unsigned u = *(const unsigned*)(tmp + (size_t)(y * RX + xx) * (BATCH * OC) + cb + cp * 2);
        tile[cp * 2][xx]     = __uint_as_float(u << 16);
        tile[cp * 2 + 1][xx] = __uint_as_float(u & 0xffff0000u);
    }
    __syncthreads();

    for (int i = threadIdx.x; i < 64 * RX; i += 256) {
        const int cl = i / RX;
        const int xx = i % RX;
        out[(size_t)(cb + cl) * (RY * RX) + y * RX + xx] = tile[cl][xx];
    }
}

// ---------------- fallback (r10 fused, verified; no workspace) ----------------
__global__ __launch_bounds__(256, 4) void lc2d_fb(
    const float* __restrict__ x, const float* __restrict__ w,
    const float* __restrict__ bias, float* __restrict__ out)
{
    __shared__ __align__(16) float wlds[4 * 2400 + 128];
    const int tid = threadIdx.x;
    const int id  = blockIdx.x;
    const int lin = (id & 7) * 450 + (id >> 3);
    const int bs  = lin & 3;
    const int pg  = lin >> 2;
    const int y   = pg / 15;
    const int x0  = (pg - y * 15) * 4;
    const int pos0 = y * RX + x0;
    const int lane = tid & 63, wid = tid >> 6;
    const int lrow = lane & 15, lgrp = lane >> 4;
    const int mt = wid >> 1, nt = wid & 1;
    const int bbase = bs * 32 + mt * 16;
    const int o = nt * 16 + lrow;

    float4 av[4][2];
    #pragma unroll
    for (int ks = 0; ks < 4; ++ks) {
        const int cm = ks * 4 + lgrp;
        if (cm < 15) {
            const int c = cm / 5, kh = cm - c * 5;
            const int b = bbase + lrow;
            const float* src = x + (size_t)((b * CIN + c) * HW + (y + kh)) * HW + x0;
            av[ks][0] = *(const float4*)(src);
            av[ks][1] = *(const float4*)(src + 4);
        }
    }
    {
        const float* gW = w + (size_t)pos0 * 2400;
        for (int j = wid; j < 38; j += 4) {
            const int chunk0 = j * 64;
            int ci = chunk0 + lane;
            if (ci > 2399) ci = 2399;
            __builtin_amdgcn_global_load_lds(
                (const __attribute__((address_space(1))) unsigned*)(gW + ci * 4),
                (__attribute__((address_space(3))) unsigned*)&wlds[chunk0 * 4],
                16, 0, 0);
        }
    }
    float bv[4];
    #pragma unroll
    for (int xi = 0; xi < 4; ++xi) bv[xi] = bias[(size_t)(pos0 + xi) * OC + o];

    short8 af[4];
    #pragma unroll
    for (int ks = 0; ks < 4; ++ks) {
        const int cm = ks * 4 + lgrp;
        union { unsigned u[4]; short8 s8; } cv;
        if (cm < 15) {
            cv.u[0] = pk2(av[ks][0].x, av[ks][0].y); cv.u[1] = pk2(av[ks][0].z, av[ks][0].w);
            cv.u[2] = pk2(av[ks][1].x, av[ks][1].y); cv.u[3] = pk2(av[ks][1].z, av[ks][1].w);
        } else { cv.u[0] = cv.u[1] = cv.u[2] = cv.u[3] = 0u; }
        af[ks] = cv.s8;
    }
    __syncthreads();

    f32x4 accx[4];
    #pragma unroll
    for (int xi = 0; xi < 4; ++xi) accx[xi] = (f32x4){0.f, 0.f, 0.f, 0.f};
    const int wbase = o * 75;
    #pragma unroll
    for (int ks = 0; ks < 4; ++ks) {
        const int cm = ks * 4 + lgrp;
        const int soff = wbase + cm * 5;
        #pragma unroll
        for (int xi = 0; xi < 4; ++xi) {
            const float* s = &wlds[xi * 2400 + soff];
            const ushort h[5] = {bf16u(s[0]), bf16u(s[1]), bf16u(s[2]), bf16u(s[3]), bf16u(s[4])};
            unsigned wd[4] = {0u, 0u, 0u, 0u};
            #pragma unroll
            for (int kw = 0; kw < 5; ++kw) {
                const int ws = xi + kw;
                wd[ws >> 1] |= (unsigned)h[kw] << ((ws & 1) * 16);
            }
            union { unsigned u[4]; short8 s8; } cv;
            cv.u[0] = wd[0]; cv.u[1] = wd[1]; cv.u[2] = wd[2]; cv.u[3] = wd[3];
            accx[xi] = __builtin_amdgcn_mfma_f32_16x16x32_bf16(af[ks], cv.s8, accx[xi], 0, 0, 0);
        }
    }
    #pragma unroll
    for (int r = 0; r < 4; ++r) {
        const int bg = bbase + lgrp * 4 + r;
        float4 v;
        v.x = accx[0][r] + bv[0]; v.y = accx[1][r] + bv[1];
        v.z = accx[2][r] + bv[2]; v.w = accx[3][r] + bv[3];
        *(float4*)(out + (size_t)(bg * OC + o) * (RY * RX) + pos0) = v;
    }
}

extern "C" void kernel_launch(void* const* d_in, const int* in_sizes, int n_in,
                              void* d_out, int out_size, void* d_ws, size_t ws_size,
                              hipStream_t stream) {
    const float* x    = (const float*)d_in[0];
    const float* w    = (const float*)d_in[1];
    const float* bias = (const float*)d_in[2];
    float* out        = (float*)d_out;

    const size_t tmp_bytes = (size_t)NPOS * BATCH * OC * sizeof(ushort);  // 29.5 MB
    if (ws_size >= tmp_bytes) {
        ushort* tmp = (ushort*)d_ws;
        lc2d_k1<<<1800, 512, 0, stream>>>(x, w, bias, tmp);
        lc2d_k2<<<dim3(64, RY), 256, 0, stream>>>(tmp, out);
    } else {
        lc2d_fb<<<3600, 256, 0, stream>>>(x, w, bias, out);
    }
}